// Round 8
// baseline (79.203 us; speedup 1.0000x reference)
//
#include <hip/hip_runtime.h>

typedef __attribute__((ext_vector_type(8))) short short8;
typedef __attribute__((ext_vector_type(8))) unsigned short ushort8;
typedef __attribute__((ext_vector_type(4))) unsigned short ushort4v;
typedef __attribute__((ext_vector_type(4))) int int4v;
typedef __attribute__((ext_vector_type(4))) float f32x4;

#define Mdim 64
#define Kdim 8192
#define Ndim 8192
#define GRP 128
#define NGRP 64
#define KSPLIT 4
#define NG2 (NGRP / KSPLIT)   // 16 groups per block (even -> x2 unroll OK)
#define BN 128

// Swizzled element offset in a [row][128]-bf16 LDS tile (256 B rows).
#define SWZ(row, kk) ((row)*128 + ((kk) ^ (8*((((row) >> 3) ^ (row)) & 7))))

__device__ __forceinline__ unsigned short f2bf(float f) {
    unsigned int u = __builtin_bit_cast(unsigned int, f);
    u += 0x7FFFu + ((u >> 16) & 1u);   // round-to-nearest-even
    return (unsigned short)(u >> 16);
}
__device__ __forceinline__ float bf2f(unsigned short h) {
    unsigned int u = ((unsigned int)h) << 16;
    return __builtin_bit_cast(float, u);
}

// Build xh/xl (hi/lo bf16 split of x) and per-(group,m) sums xsum[g][m].
__global__ void prep_kernel(const float* __restrict__ x,
                            unsigned short* __restrict__ xh,
                            unsigned short* __restrict__ xl,
                            float* __restrict__ xsum) {
    const int tid = threadIdx.x;
    const int u = blockIdx.x * 8 + (tid >> 5);
    const int g = u & (NGRP - 1);
    const int m = u >> 6;
    const int lane = tid & 31;
    const int k = g * GRP + lane * 4;
    f32x4 v = *(const f32x4*)(x + (size_t)m * Kdim + k);
    ushort4v hv, lv;
    float s = 0.f;
#pragma unroll
    for (int i = 0; i < 4; ++i) {
        unsigned short h = f2bf(v[i]);
        hv[i] = h;
        lv[i] = f2bf(v[i] - bf2f(h));
        s += v[i];
    }
    *(ushort4v*)(xh + (size_t)m * Kdim + k) = hv;
    *(ushort4v*)(xl + (size_t)m * Kdim + k) = lv;
#pragma unroll
    for (int off = 16; off > 0; off >>= 1) s += __shfl_down(s, off, 32);
    if (lane == 0) xsum[g * Mdim + m] = s;
}

// q load: 8 rows x 16B per thread into a named reg set (static indices only)
#define LOADQ_M(dst, g) do {                                                  \
    const size_t kb_ = (size_t)(g) * GRP + qr * 8;                            \
    const int nc_ = n0 + qc * 4;                                              \
    _Pragma("unroll")                                                         \
    for (int j = 0; j < 8; ++j)                                               \
        dst[j] = *(const int4v*)(qw + (kb_ + j) * Ndim + nc_);                \
} while (0)

// exact int->bf16 (|q|<=128 => truncation exact), b128 swizzled LDS writes
#define WRITEQ_M(src, bb) do {                                                \
    _Pragma("unroll")                                                         \
    for (int i = 0; i < 4; ++i) {                                             \
        int4v pk_;                                                            \
        _Pragma("unroll")                                                     \
        for (int t = 0; t < 4; ++t) {                                         \
            unsigned lo_ = __builtin_bit_cast(unsigned, (float)src[2*t][i]) >> 16;        \
            unsigned hi_ = __builtin_bit_cast(unsigned, (float)src[2*t+1][i]) & 0xFFFF0000u; \
            pk_[t] = (int)(lo_ | hi_);                                        \
        }                                                                     \
        *(int4v*)&lq[bb][SWZ(qc * 4 + i, qr * 8)] = pk_;                      \
    }                                                                         \
} while (0)

// Main: 256 blocks = 64 n-tiles (BN=128) x KSPLIT=4. 512 threads = 8 waves,
// wave = 64m x 16n. q: 2-deep register pipeline (qva/qvb) + double-buffered
// LDS -> 1-2 groups of q ALWAYS in flight; the only vm-wait per iter is for
// loads issued a full iteration earlier. Lockstep barriers keep the 64-block
// cohort on the same k-rows (DRAM row coherence, the R7 win).
__launch_bounds__(512, 2)
__global__ void qlin_kernel(const unsigned short* __restrict__ xh,
                            const unsigned short* __restrict__ xl,
                            const int* __restrict__ qw,
                            const float* __restrict__ scales,
                            const float* __restrict__ zeros,
                            const float* __restrict__ xsum,
                            float* __restrict__ pout) {
    __shared__ unsigned short lq[2][128 * 128];   // [buf][SWZ(n,k)] 32 KB each
    __shared__ unsigned short lxh[64 * 128];      // [SWZ(m,k)] 16 KB
    __shared__ unsigned short lxl[64 * 128];      // 16 KB

    const int tid = threadIdx.x;
    const int kh = blockIdx.x & (KSPLIT - 1);
    const int n0 = (blockIdx.x >> 2) * BN;
    const int g0 = kh * NG2;

    const int w = tid >> 6;       // wave 0..7 -> n-strip
    const int l = tid & 63;
    const int lcol = l & 15;
    const int lhi = l >> 4;

    const int qc = tid & 31;      // q staging: 16B col-chunk
    const int qr = tid >> 5;      // q staging: row octet
    const int xc = tid & 15;      // x staging: 8-elem chunk
    const int xm = tid >> 4;      // x staging: row

    const int nn = n0 + w * 16 + lcol;   // this lane's output column

    int4v qva[8], qvb[8];
    ushort8 xga, xgb, xgc, xgd;
    float s_n, z_n, s_c, z_c;
    f32x4 xs_n[4], xs_c[4];

    auto LOAD_SZX = [&](int g) {
        s_n = scales[(size_t)g * Ndim + nn];
        z_n = zeros[(size_t)g * Ndim + nn];
#pragma unroll
        for (int mf = 0; mf < 4; ++mf)
            xs_n[mf] = *(const f32x4*)(xsum + g * Mdim + mf * 16 + lhi * 4);
    };
    auto LOADX = [&](int g) {
        const size_t kb = (size_t)g * GRP + xc * 8;
        xga = *(const ushort8*)(xh + (size_t)xm * Kdim + kb);
        xgb = *(const ushort8*)(xh + (size_t)(xm + 32) * Kdim + kb);
        xgc = *(const ushort8*)(xl + (size_t)xm * Kdim + kb);
        xgd = *(const ushort8*)(xl + (size_t)(xm + 32) * Kdim + kb);
    };
    auto WRITEX = [&]() {
        *(ushort8*)&lxh[SWZ(xm, xc * 8)] = xga;
        *(ushort8*)&lxh[SWZ(xm + 32, xc * 8)] = xgb;
        *(ushort8*)&lxl[SWZ(xm, xc * 8)] = xgc;
        *(ushort8*)&lxl[SWZ(xm + 32, xc * 8)] = xgd;
    };

    f32x4 acc[4];
#pragma unroll
    for (int mf = 0; mf < 4; ++mf) acc[mf] = {0.f, 0.f, 0.f, 0.f};

    auto COMPUTE = [&](int g) {   // lgkm-only phase
        const int bb = g & 1;
        short8 bq[4];
#pragma unroll
        for (int ks = 0; ks < 4; ++ks)
            bq[ks] = *(const short8*)&lq[bb][SWZ(w * 16 + lcol, ks * 32 + lhi * 8)];
#pragma unroll
        for (int mf = 0; mf < 4; ++mf) {
            short8 ah[4], al[4];
#pragma unroll
            for (int ks = 0; ks < 4; ++ks) {
                ah[ks] = *(const short8*)&lxh[SWZ(mf * 16 + lcol, ks * 32 + lhi * 8)];
                al[ks] = *(const short8*)&lxl[SWZ(mf * 16 + lcol, ks * 32 + lhi * 8)];
            }
            f32x4 p = {0.f, 0.f, 0.f, 0.f};
#pragma unroll
            for (int ks = 0; ks < 4; ++ks) {
                p = __builtin_amdgcn_mfma_f32_16x16x32_bf16(ah[ks], bq[ks], p, 0, 0, 0);
                p = __builtin_amdgcn_mfma_f32_16x16x32_bf16(al[ks], bq[ks], p, 0, 0, 0);
            }
#pragma unroll
            for (int r = 0; r < 4; ++r)
                acc[mf][r] += s_c * (p[r] - z_c * xs_c[mf][r]);
        }
    };

    // prologue: stage g0; then refill qva with q(g0+1)
    LOAD_SZX(g0);
    LOADX(g0);
    LOADQ_M(qva, g0);
    s_c = s_n; z_c = z_n;
#pragma unroll
    for (int mf = 0; mf < 4; ++mf) xs_c[mf] = xs_n[mf];
    WRITEX();
    WRITEQ_M(qva, 0);             // vmcnt(0) once
    LOADQ_M(qva, g0 + 1);         // q(g0+1) in flight
    __syncthreads();

#define STEP(G, CUR, NXT) do {                                                \
    const int g_ = (G);                                                       \
    const bool m1_ = (g_ + 1 < NG2);                                          \
    const bool m2_ = (g_ + 2 < NG2);                                          \
    if (m1_) { LOAD_SZX(g0 + g_ + 1); LOADX(g0 + g_ + 1); }                   \
    if (m2_) LOADQ_M(NXT, g0 + g_ + 2);                                       \
    COMPUTE(g_);                                                              \
    if (m1_) {                                                                \
        __syncthreads();                                                      \
        s_c = s_n; z_c = z_n;                                                 \
        _Pragma("unroll")                                                     \
        for (int mf = 0; mf < 4; ++mf) xs_c[mf] = xs_n[mf];                   \
        WRITEX();                                                             \
        WRITEQ_M(CUR, (g_ + 1) & 1);                                          \
        __syncthreads();                                                      \
    }                                                                         \
} while (0)

    for (int gg = 0; gg < NG2; gg += 2) {
        STEP(gg, qva, qvb);
        STEP(gg + 1, qvb, qva);
    }
#undef STEP

    const size_t ob = (size_t)kh * Mdim * Ndim;
#pragma unroll
    for (int mf = 0; mf < 4; ++mf)
#pragma unroll
        for (int r = 0; r < 4; ++r)
            pout[ob + (size_t)(mf * 16 + lhi * 4 + r) * Ndim + nn] = acc[mf][r];
}

// out = sum of KSPLIT partials + bias
__global__ void reduce_kernel(const float* __restrict__ pout,
                              const float* __restrict__ bias,
                              float* __restrict__ out) {
    const size_t e = ((size_t)blockIdx.x * 256 + threadIdx.x) * 4;
    const int n = (int)(e & (Ndim - 1));
    f32x4 a = *(const f32x4*)(bias + n);
#pragma unroll
    for (int s = 0; s < KSPLIT; ++s) {
        f32x4 ppart = *(const f32x4*)(pout + (size_t)s * Mdim * Ndim + e);
#pragma unroll
        for (int r = 0; r < 4; ++r) a[r] += ppart[r];
    }
    *(f32x4*)(out + e) = a;
}

extern "C" void kernel_launch(void* const* d_in, const int* in_sizes, int n_in,
                              void* d_out, int out_size, void* d_ws, size_t ws_size,
                              hipStream_t stream) {
    const float* x = (const float*)d_in[0];
    const int* qw = (const int*)d_in[1];
    const float* scales = (const float*)d_in[2];
    const float* zeros = (const float*)d_in[3];
    const float* bias = (const float*)d_in[4];

    unsigned short* xh = (unsigned short*)d_ws;
    unsigned short* xl = xh + (size_t)Mdim * Kdim;
    float* xsum = (float*)(xl + (size_t)Mdim * Kdim);
    float* pout = xsum + NGRP * Mdim;
    float* out = (float*)d_out;

    prep_kernel<<<512, 256, 0, stream>>>(x, xh, xl, xsum);
    qlin_kernel<<<(Ndim / BN) * KSPLIT, 512, 0, stream>>>(xh, xl, qw, scales, zeros, xsum, pout);
    reduce_kernel<<<(Mdim * Ndim / 4) / 256, 256, 0, stream>>>(pout, bias, out);
}

// Round 9
// 66.697 us; speedup vs baseline: 1.1875x; 1.1875x over previous
//
#include <hip/hip_runtime.h>

typedef __attribute__((ext_vector_type(8))) short short8;
typedef __attribute__((ext_vector_type(8))) unsigned short ushort8;
typedef __attribute__((ext_vector_type(4))) unsigned short ushort4v;
typedef __attribute__((ext_vector_type(4))) int int4v;
typedef __attribute__((ext_vector_type(4))) float f32x4;

#define Mdim 64
#define Kdim 8192
#define Ndim 8192
#define GRP 128
#define NGRP 64
#define KSPLIT 4
#define NG2 (NGRP / KSPLIT)   // 16 groups per block
#define BN 128

// Swizzled element offset in a [row][128]-bf16 LDS tile (256 B rows).
#define SWZ(row, kk) ((row)*128 + ((kk) ^ (8*((((row) >> 3) ^ (row)) & 7))))

__device__ __forceinline__ unsigned short f2bf(float f) {
    unsigned int u = __builtin_bit_cast(unsigned int, f);
    u += 0x7FFFu + ((u >> 16) & 1u);   // round-to-nearest-even
    return (unsigned short)(u >> 16);
}
__device__ __forceinline__ float bf2f(unsigned short h) {
    unsigned int u = ((unsigned int)h) << 16;
    return __builtin_bit_cast(float, u);
}

// Build xh/xl (hi/lo bf16 split of x) and per-(group,m) sums xsum[g][m].
__global__ void prep_kernel(const float* __restrict__ x,
                            unsigned short* __restrict__ xh,
                            unsigned short* __restrict__ xl,
                            float* __restrict__ xsum) {
    const int tid = threadIdx.x;
    const int u = blockIdx.x * 8 + (tid >> 5);
    const int g = u & (NGRP - 1);
    const int m = u >> 6;
    const int lane = tid & 31;
    const int k = g * GRP + lane * 4;
    f32x4 v = *(const f32x4*)(x + (size_t)m * Kdim + k);
    ushort4v hv, lv;
    float s = 0.f;
#pragma unroll
    for (int i = 0; i < 4; ++i) {
        unsigned short h = f2bf(v[i]);
        hv[i] = h;
        lv[i] = f2bf(v[i] - bf2f(h));
        s += v[i];
    }
    *(ushort4v*)(xh + (size_t)m * Kdim + k) = hv;
    *(ushort4v*)(xl + (size_t)m * Kdim + k) = lv;
#pragma unroll
    for (int off = 16; off > 0; off >>= 1) s += __shfl_down(s, off, 32);
    if (lane == 0) xsum[g * Mdim + m] = s;
}

// Main: 256 blocks = 64 n-tiles (BN=128) x KSPLIT=4. 512 threads = 8 waves,
// wave = 64m x 16n. R7 structure (1-deep q pipeline, double-buffered q LDS,
// single-buffered x LDS, lockstep barriers for DRAM row coherence) PLUS:
//  - parity phase-offset: odd n-tiles process groups rotated by NG2/2, so the
//    two half-cohorts' per-iter bubbles interleave and HBM demand stays flat;
//  - single vm-drain point per iter (WRITEQ first after the barrier).
__launch_bounds__(512)
__global__ void qlin_kernel(const unsigned short* __restrict__ xh,
                            const unsigned short* __restrict__ xl,
                            const int* __restrict__ qw,
                            const float* __restrict__ scales,
                            const float* __restrict__ zeros,
                            const float* __restrict__ xsum,
                            float* __restrict__ pout) {
    __shared__ unsigned short lq[2][128 * 128];   // [buf][SWZ(n,k)] 32 KB each
    __shared__ unsigned short lxh[64 * 128];      // [SWZ(m,k)] 16 KB
    __shared__ unsigned short lxl[64 * 128];      // 16 KB

    const int tid = threadIdx.x;
    const int kh = blockIdx.x & (KSPLIT - 1);
    const int n0 = (blockIdx.x >> 2) * BN;
    const int g0 = kh * NG2;
    const int ph = ((blockIdx.x >> 2) & 1) * (NG2 / 2);   // phase offset

    const int w = tid >> 6;       // wave 0..7 -> n-strip
    const int l = tid & 63;
    const int lcol = l & 15;
    const int lhi = l >> 4;

    const int qc = tid & 31;      // q staging: 16B col-chunk
    const int qr = tid >> 5;      // q staging: row octet
    const int xc = tid & 15;      // x staging: 8-elem chunk
    const int xm = tid >> 4;      // x staging: row

    const int nn = n0 + w * 16 + lcol;   // this lane's output column

    int4v qv[8];
    ushort8 xga, xgb, xgc, xgd;
    float s_n, z_n, s_c, z_c;
    f32x4 xs_n[4], xs_c[4];

    auto LOAD_SZX = [&](int g) {
        s_n = scales[(size_t)g * Ndim + nn];
        z_n = zeros[(size_t)g * Ndim + nn];
#pragma unroll
        for (int mf = 0; mf < 4; ++mf)
            xs_n[mf] = *(const f32x4*)(xsum + g * Mdim + mf * 16 + lhi * 4);
    };
    auto LOADX = [&](int g) {
        const size_t kb = (size_t)g * GRP + xc * 8;
        xga = *(const ushort8*)(xh + (size_t)xm * Kdim + kb);
        xgb = *(const ushort8*)(xh + (size_t)(xm + 32) * Kdim + kb);
        xgc = *(const ushort8*)(xl + (size_t)xm * Kdim + kb);
        xgd = *(const ushort8*)(xl + (size_t)(xm + 32) * Kdim + kb);
    };
    auto LOADQ = [&](int g) {     // issue LAST (youngest in vmcnt queue)
        const size_t kb = (size_t)g * GRP + qr * 8;
        const int nc = n0 + qc * 4;
#pragma unroll
        for (int j = 0; j < 8; ++j)
            qv[j] = *(const int4v*)(qw + (kb + j) * Ndim + nc);
    };
    auto WRITEX = [&]() {
        *(ushort8*)&lxh[SWZ(xm, xc * 8)] = xga;
        *(ushort8*)&lxh[SWZ(xm + 32, xc * 8)] = xgb;
        *(ushort8*)&lxl[SWZ(xm, xc * 8)] = xgc;
        *(ushort8*)&lxl[SWZ(xm + 32, xc * 8)] = xgd;
    };
    auto WRITEQ = [&](int bb) {   // exact int->bf16 (|q|<=128 => truncation exact)
#pragma unroll
        for (int i = 0; i < 4; ++i) {
            int4v pk;
#pragma unroll
            for (int t = 0; t < 4; ++t) {
                unsigned lo = __builtin_bit_cast(unsigned, (float)qv[2 * t][i]) >> 16;
                unsigned hi = __builtin_bit_cast(unsigned, (float)qv[2 * t + 1][i]) & 0xFFFF0000u;
                pk[t] = (int)(lo | hi);
            }
            *(int4v*)&lq[bb][SWZ(qc * 4 + i, qr * 8)] = pk;
        }
    };

    f32x4 acc[4];
#pragma unroll
    for (int mf = 0; mf < 4; ++mf) acc[mf] = {0.f, 0.f, 0.f, 0.f};

    auto COMPUTE = [&](int bb) {  // lgkm-only phase
        short8 bq[4];
#pragma unroll
        for (int ks = 0; ks < 4; ++ks)
            bq[ks] = *(const short8*)&lq[bb][SWZ(w * 16 + lcol, ks * 32 + lhi * 8)];
#pragma unroll
        for (int mf = 0; mf < 4; ++mf) {
            short8 ah[4], al[4];
#pragma unroll
            for (int ks = 0; ks < 4; ++ks) {
                ah[ks] = *(const short8*)&lxh[SWZ(mf * 16 + lcol, ks * 32 + lhi * 8)];
                al[ks] = *(const short8*)&lxl[SWZ(mf * 16 + lcol, ks * 32 + lhi * 8)];
            }
            f32x4 p = {0.f, 0.f, 0.f, 0.f};
#pragma unroll
            for (int ks = 0; ks < 4; ++ks) {
                p = __builtin_amdgcn_mfma_f32_16x16x32_bf16(ah[ks], bq[ks], p, 0, 0, 0);
                p = __builtin_amdgcn_mfma_f32_16x16x32_bf16(al[ks], bq[ks], p, 0, 0, 0);
            }
#pragma unroll
            for (int r = 0; r < 4; ++r)
                acc[mf][r] += s_c * (p[r] - z_c * xs_c[mf][r]);
        }
    };

    // prologue: stage group gs(0)
    {
        const int ga = g0 + ph;
        LOAD_SZX(ga);
        LOADX(ga);
        LOADQ(ga);
        s_c = s_n; z_c = z_n;
#pragma unroll
        for (int mf = 0; mf < 4; ++mf) xs_c[mf] = xs_n[mf];
        WRITEX();
        WRITEQ(0);
        __syncthreads();
    }

    for (int g = 0; g < NG2; ++g) {
        const int bb = g & 1;
        const bool more = (g + 1 < NG2);

        // prefetch issue for gs(g+1): sz/x first, q LAST (stays in flight)
        if (more) {
            const int ga = g0 + ((g + 1 + ph) & (NG2 - 1));
            LOAD_SZX(ga);
            LOADX(ga);
            LOADQ(ga);
        }

        COMPUTE(bb);

        if (more) {
            __syncthreads();              // all reads of x-buf and lq[bb] done
            WRITEQ(bb ^ 1);               // single drain point (q youngest)
            s_c = s_n; z_c = z_n;
#pragma unroll
            for (int mf = 0; mf < 4; ++mf) xs_c[mf] = xs_n[mf];
            WRITEX();
            __syncthreads();              // staging visible for next iter
        }
    }

    const size_t ob = (size_t)kh * Mdim * Ndim;
#pragma unroll
    for (int mf = 0; mf < 4; ++mf)
#pragma unroll
        for (int r = 0; r < 4; ++r)
            pout[ob + (size_t)(mf * 16 + lhi * 4 + r) * Ndim + nn] = acc[mf][r];
}

// out = sum of KSPLIT partials + bias
__global__ void reduce_kernel(const float* __restrict__ pout,
                              const float* __restrict__ bias,
                              float* __restrict__ out) {
    const size_t e = ((size_t)blockIdx.x * 256 + threadIdx.x) * 4;
    const int n = (int)(e & (Ndim - 1));
    f32x4 a = *(const f32x4*)(bias + n);
#pragma unroll
    for (int s = 0; s < KSPLIT; ++s) {
        f32x4 ppart = *(const f32x4*)(pout + (size_t)s * Mdim * Ndim + e);
#pragma unroll
        for (int r = 0; r < 4; ++r) a[r] += ppart[r];
    }
    *(f32x4*)(out + e) = a;
}

extern "C" void kernel_launch(void* const* d_in, const int* in_sizes, int n_in,
                              void* d_out, int out_size, void* d_ws, size_t ws_size,
                              hipStream_t stream) {
    const float* x = (const float*)d_in[0];
    const int* qw = (const int*)d_in[1];
    const float* scales = (const float*)d_in[2];
    const float* zeros = (const float*)d_in[3];
    const float* bias = (const float*)d_in[4];

    unsigned short* xh = (unsigned short*)d_ws;
    unsigned short* xl = xh + (size_t)Mdim * Kdim;
    float* xsum = (float*)(xl + (size_t)Mdim * Kdim);
    float* pout = xsum + NGRP * Mdim;
    float* out = (float*)d_out;

    prep_kernel<<<512, 256, 0, stream>>>(x, xh, xl, xsum);
    qlin_kernel<<<(Ndim / BN) * KSPLIT, 512, 0, stream>>>(xh, xl, qw, scales, zeros, xsum, pout);
    reduce_kernel<<<(Mdim * Ndim / 4) / 256, 256, 0, stream>>>(pout, bias, out);
}

// Round 10
// 61.525 us; speedup vs baseline: 1.2873x; 1.0841x over previous
//
#include <hip/hip_runtime.h>

typedef __attribute__((ext_vector_type(8))) short short8;
typedef __attribute__((ext_vector_type(8))) unsigned short ushort8;
typedef __attribute__((ext_vector_type(4))) unsigned short ushort4v;
typedef __attribute__((ext_vector_type(4))) int int4v;
typedef __attribute__((ext_vector_type(4))) float f32x4;

#define Mdim 64
#define Kdim 8192
#define Ndim 8192
#define GRP 128
#define NGRP 64
#define KSPLIT 8
#define NG2 (NGRP / KSPLIT)   // 8 groups per block
#define BN 128

// Swizzled element offset in a [row][128]-bf16 LDS tile (256 B rows).
#define SWZ(row, kk) ((row)*128 + ((kk) ^ (8*((((row) >> 3) ^ (row)) & 7))))

__device__ __forceinline__ unsigned short f2bf(float f) {
    unsigned int u = __builtin_bit_cast(unsigned int, f);
    u += 0x7FFFu + ((u >> 16) & 1u);   // round-to-nearest-even
    return (unsigned short)(u >> 16);
}
__device__ __forceinline__ float bf2f(unsigned short h) {
    unsigned int u = ((unsigned int)h) << 16;
    return __builtin_bit_cast(float, u);
}

// Build xh/xl (hi/lo bf16 split of x) and per-(group,m) sums xsum[g][m].
__global__ void prep_kernel(const float* __restrict__ x,
                            unsigned short* __restrict__ xh,
                            unsigned short* __restrict__ xl,
                            float* __restrict__ xsum) {
    const int tid = threadIdx.x;
    const int u = blockIdx.x * 8 + (tid >> 5);
    const int g = u & (NGRP - 1);
    const int m = u >> 6;
    const int lane = tid & 31;
    const int k = g * GRP + lane * 4;
    f32x4 v = *(const f32x4*)(x + (size_t)m * Kdim + k);
    ushort4v hv, lv;
    float s = 0.f;
#pragma unroll
    for (int i = 0; i < 4; ++i) {
        unsigned short h = f2bf(v[i]);
        hv[i] = h;
        lv[i] = f2bf(v[i] - bf2f(h));
        s += v[i];
    }
    *(ushort4v*)(xh + (size_t)m * Kdim + k) = hv;
    *(ushort4v*)(xl + (size_t)m * Kdim + k) = lv;
#pragma unroll
    for (int off = 16; off > 0; off >>= 1) s += __shfl_down(s, off, 32);
    if (lane == 0) xsum[g * Mdim + m] = s;
}

// Main: 512 blocks = 64 n-tiles (BN=128) x KSPLIT=8 (kh=bid&7 -> one kh per
// XCD; x k-slice L2-resident). 2 blocks/CU (74 KB LDS, VGPR<=128): while one
// block drains its q staging, the sibling computes -> HBM demand stays up.
// 512 threads = 8 waves = 2 m-tiles(32) x 4 n-strips(32); 24 ds_reads/wave/grp.
// Epilogue tables (scales/zeros/xsum) prologue-staged into LDS: the k-loop's
// only vmem are x(4) + q(8) loads, x issued first -> WRITEX waits vmcnt(8)
// (q stays in flight), WRITEQ is the single drain, covered by the sibling.
__launch_bounds__(512, 4)
__global__ void qlin_kernel(const unsigned short* __restrict__ xh,
                            const unsigned short* __restrict__ xl,
                            const int* __restrict__ qw,
                            const float* __restrict__ scales,
                            const float* __restrict__ zeros,
                            const float* __restrict__ xsum,
                            float* __restrict__ pout) {
    __shared__ unsigned short lq[128 * 128];   // 32 KB, [SWZ(n,k)] single-buffered
    __shared__ unsigned short lxh[64 * 128];   // 16 KB
    __shared__ unsigned short lxl[64 * 128];   // 16 KB
    __shared__ float ls[NG2][128];             // 4 KB scales slice
    __shared__ float lz[NG2][128];             // 4 KB zeros slice
    __shared__ float lxs[NG2][64];             // 2 KB xsum slice

    const int tid = threadIdx.x;
    const int kh = blockIdx.x & (KSPLIT - 1);
    const int n0 = (blockIdx.x >> 3) * BN;
    const int g0 = kh * NG2;
    const int ph = ((blockIdx.x >> 8) & 1) * (NG2 / 2);  // anti-phase CU siblings

    const int w = tid >> 6;
    const int l = tid & 63;
    const int lcol = l & 15;
    const int lhi = l >> 4;
    const int mt = (w >> 2) * 32;     // m-tile base: 0 or 32
    const int ns = (w & 3) * 32;      // n-strip base: 0,32,64,96

    const int qc = tid & 31;          // q staging: 16B col-chunk
    const int qr = tid >> 5;          // q staging: row octet
    const int xc = tid & 15;          // x staging: 8-elem chunk
    const int xm = tid >> 4;          // x staging: row

    const int c0 = n0 + ns + lcol;    // output cols (nf=0,1)
    const int c1 = c0 + 16;

    int4v qv[8];
    ushort8 xga, xgb, xgc, xgd;

    auto LOADX = [&](int g) {         // issue BEFORE LOADQ each iter
        const size_t kb = (size_t)g * GRP + xc * 8;
        xga = *(const ushort8*)(xh + (size_t)xm * Kdim + kb);
        xgb = *(const ushort8*)(xh + (size_t)(xm + 32) * Kdim + kb);
        xgc = *(const ushort8*)(xl + (size_t)xm * Kdim + kb);
        xgd = *(const ushort8*)(xl + (size_t)(xm + 32) * Kdim + kb);
    };
    auto LOADQ = [&](int g) {         // youngest in vmcnt queue
        const size_t kb = (size_t)g * GRP + qr * 8;
        const int nc = n0 + qc * 4;
#pragma unroll
        for (int j = 0; j < 8; ++j)
            qv[j] = *(const int4v*)(qw + (kb + j) * Ndim + nc);
    };
    auto WRITEX = [&]() {
        *(ushort8*)&lxh[SWZ(xm, xc * 8)] = xga;
        *(ushort8*)&lxh[SWZ(xm + 32, xc * 8)] = xgb;
        *(ushort8*)&lxl[SWZ(xm, xc * 8)] = xgc;
        *(ushort8*)&lxl[SWZ(xm + 32, xc * 8)] = xgd;
    };
    auto WRITEQ = [&]() {             // exact int->bf16 (|q|<=128 => truncation exact)
#pragma unroll
        for (int i = 0; i < 4; ++i) {
            int4v pk;
#pragma unroll
            for (int t = 0; t < 4; ++t) {
                unsigned lo = __builtin_bit_cast(unsigned, (float)qv[2 * t][i]) >> 16;
                unsigned hi = __builtin_bit_cast(unsigned, (float)qv[2 * t + 1][i]) & 0xFFFF0000u;
                pk[t] = (int)(lo | hi);
            }
            *(int4v*)&lq[SWZ(qc * 4 + i, qr * 8)] = pk;
        }
    };

    f32x4 acc00 = {0,0,0,0}, acc01 = {0,0,0,0}, acc10 = {0,0,0,0}, acc11 = {0,0,0,0};

    // ---- prologue: stage epilogue tables + group gs(0); one full drain ----
    if (tid < 256) {
        *(f32x4*)&ls[tid >> 5][(tid & 31) * 4] =
            *(const f32x4*)(scales + (size_t)(g0 + (tid >> 5)) * Ndim + n0 + (tid & 31) * 4);
    } else {
        const int t = tid - 256;
        *(f32x4*)&lz[t >> 5][(t & 31) * 4] =
            *(const f32x4*)(zeros + (size_t)(g0 + (t >> 5)) * Ndim + n0 + (t & 31) * 4);
    }
    lxs[tid >> 6][tid & 63] = xsum[(g0 + (tid >> 6)) * Mdim + (tid & 63)];
    {
        const int ga = g0 + ph;
        LOADX(ga);
        LOADQ(ga);
        WRITEX();
        WRITEQ();
        __syncthreads();
    }

    for (int g = 0; g < NG2; ++g) {
        const int gi = (g + ph) & (NG2 - 1);
        const bool more = (g + 1 < NG2);

        if (more) {
            const int ga = g0 + ((g + 1 + ph) & (NG2 - 1));
            LOADX(ga);                // older than q
            LOADQ(ga);                // stays in flight through COMPUTE
        }

        // compute phase: lgkm-only
        f32x4 p00 = {0,0,0,0}, p01 = {0,0,0,0}, p10 = {0,0,0,0}, p11 = {0,0,0,0};
#pragma unroll
        for (int ks = 0; ks < 4; ++ks) {
            const int kk = ks * 32 + lhi * 8;
            short8 bq0 = *(const short8*)&lq[SWZ(ns + lcol, kk)];
            short8 bq1 = *(const short8*)&lq[SWZ(ns + 16 + lcol, kk)];
            short8 ah0 = *(const short8*)&lxh[SWZ(mt + lcol, kk)];
            short8 al0 = *(const short8*)&lxl[SWZ(mt + lcol, kk)];
            short8 ah1 = *(const short8*)&lxh[SWZ(mt + 16 + lcol, kk)];
            short8 al1 = *(const short8*)&lxl[SWZ(mt + 16 + lcol, kk)];
            p00 = __builtin_amdgcn_mfma_f32_16x16x32_bf16(ah0, bq0, p00, 0, 0, 0);
            p00 = __builtin_amdgcn_mfma_f32_16x16x32_bf16(al0, bq0, p00, 0, 0, 0);
            p01 = __builtin_amdgcn_mfma_f32_16x16x32_bf16(ah0, bq1, p01, 0, 0, 0);
            p01 = __builtin_amdgcn_mfma_f32_16x16x32_bf16(al0, bq1, p01, 0, 0, 0);
            p10 = __builtin_amdgcn_mfma_f32_16x16x32_bf16(ah1, bq0, p10, 0, 0, 0);
            p10 = __builtin_amdgcn_mfma_f32_16x16x32_bf16(al1, bq0, p10, 0, 0, 0);
            p11 = __builtin_amdgcn_mfma_f32_16x16x32_bf16(ah1, bq1, p11, 0, 0, 0);
            p11 = __builtin_amdgcn_mfma_f32_16x16x32_bf16(al1, bq1, p11, 0, 0, 0);
        }
        // group fold: all operands from LDS (no vmcnt interaction)
        {
            const float s0 = ls[gi][ns + lcol],      z0 = lz[gi][ns + lcol];
            const float s1 = ls[gi][ns + 16 + lcol], z1 = lz[gi][ns + 16 + lcol];
            f32x4 xs0 = *(const f32x4*)&lxs[gi][mt + lhi * 4];
            f32x4 xs1 = *(const f32x4*)&lxs[gi][mt + 16 + lhi * 4];
#pragma unroll
            for (int r = 0; r < 4; ++r) {
                acc00[r] += s0 * (p00[r] - z0 * xs0[r]);
                acc01[r] += s1 * (p01[r] - z1 * xs0[r]);
                acc10[r] += s0 * (p10[r] - z0 * xs1[r]);
                acc11[r] += s1 * (p11[r] - z1 * xs1[r]);
            }
        }

        if (more) {
            __syncthreads();          // all LDS reads of this group done
            WRITEX();                 // vmcnt(8): x landed, q still in flight
            WRITEQ();                 // vmcnt(0): the one drain; sibling covers
            __syncthreads();
        }
    }

    const size_t ob = (size_t)kh * Mdim * Ndim;
#pragma unroll
    for (int r = 0; r < 4; ++r) {
        pout[ob + (size_t)(mt + lhi * 4 + r) * Ndim + c0] = acc00[r];
        pout[ob + (size_t)(mt + lhi * 4 + r) * Ndim + c1] = acc01[r];
        pout[ob + (size_t)(mt + 16 + lhi * 4 + r) * Ndim + c0] = acc10[r];
        pout[ob + (size_t)(mt + 16 + lhi * 4 + r) * Ndim + c1] = acc11[r];
    }
}

// out = sum of KSPLIT partials + bias
__global__ void reduce_kernel(const float* __restrict__ pout,
                              const float* __restrict__ bias,
                              float* __restrict__ out) {
    const size_t e = ((size_t)blockIdx.x * 256 + threadIdx.x) * 4;
    const int n = (int)(e & (Ndim - 1));
    f32x4 a = *(const f32x4*)(bias + n);
#pragma unroll
    for (int s = 0; s < KSPLIT; ++s) {
        f32x4 ppart = *(const f32x4*)(pout + (size_t)s * Mdim * Ndim + e);
#pragma unroll
        for (int r = 0; r < 4; ++r) a[r] += ppart[r];
    }
    *(f32x4*)(out + e) = a;
}

extern "C" void kernel_launch(void* const* d_in, const int* in_sizes, int n_in,
                              void* d_out, int out_size, void* d_ws, size_t ws_size,
                              hipStream_t stream) {
    const float* x = (const float*)d_in[0];
    const int* qw = (const int*)d_in[1];
    const float* scales = (const float*)d_in[2];
    const float* zeros = (const float*)d_in[3];
    const float* bias = (const float*)d_in[4];

    unsigned short* xh = (unsigned short*)d_ws;
    unsigned short* xl = xh + (size_t)Mdim * Kdim;
    float* xsum = (float*)(xl + (size_t)Mdim * Kdim);
    float* pout = xsum + NGRP * Mdim;
    float* out = (float*)d_out;

    prep_kernel<<<512, 256, 0, stream>>>(x, xh, xl, xsum);
    qlin_kernel<<<(Ndim / BN) * KSPLIT, 512, 0, stream>>>(xh, xl, qw, scales, zeros, xsum, pout);
    reduce_kernel<<<(Mdim * Ndim / 4) / 256, 256, 0, stream>>>(pout, bias, out);
}

// Round 11
// 56.231 us; speedup vs baseline: 1.4085x; 1.0941x over previous
//
#include <hip/hip_runtime.h>

typedef __attribute__((ext_vector_type(8))) short short8;
typedef __attribute__((ext_vector_type(8))) unsigned short ushort8;
typedef __attribute__((ext_vector_type(4))) unsigned short ushort4v;
typedef __attribute__((ext_vector_type(4))) int int4v;
typedef __attribute__((ext_vector_type(4))) float f32x4;

#define Mdim 64
#define Kdim 8192
#define Ndim 8192
#define GRP 128
#define NGRP 64
#define KSPLIT 4
#define NG2 (NGRP / KSPLIT)   // 16 groups per block
#define BN 128

// Swizzled element offset in a [row][128]-bf16 LDS tile (256 B rows).
#define SWZ(row, kk) ((row)*128 + ((kk) ^ (8*((((row) >> 3) ^ (row)) & 7))))

__device__ __forceinline__ unsigned short f2bf(float f) {
    unsigned int u = __builtin_bit_cast(unsigned int, f);
    u += 0x7FFFu + ((u >> 16) & 1u);   // round-to-nearest-even
    return (unsigned short)(u >> 16);
}
__device__ __forceinline__ float bf2f(unsigned short h) {
    unsigned int u = ((unsigned int)h) << 16;
    return __builtin_bit_cast(float, u);
}

// Build xh/xl (hi/lo bf16 split of x) and per-(group,m) sums xsum[g][m].
__global__ void prep_kernel(const float* __restrict__ x,
                            unsigned short* __restrict__ xh,
                            unsigned short* __restrict__ xl,
                            float* __restrict__ xsum) {
    const int tid = threadIdx.x;
    const int u = blockIdx.x * 8 + (tid >> 5);
    const int g = u & (NGRP - 1);
    const int m = u >> 6;
    const int lane = tid & 31;
    const int k = g * GRP + lane * 4;
    f32x4 v = *(const f32x4*)(x + (size_t)m * Kdim + k);
    ushort4v hv, lv;
    float s = 0.f;
#pragma unroll
    for (int i = 0; i < 4; ++i) {
        unsigned short h = f2bf(v[i]);
        hv[i] = h;
        lv[i] = f2bf(v[i] - bf2f(h));
        s += v[i];
    }
    *(ushort4v*)(xh + (size_t)m * Kdim + k) = hv;
    *(ushort4v*)(xl + (size_t)m * Kdim + k) = lv;
#pragma unroll
    for (int off = 16; off > 0; off >>= 1) s += __shfl_down(s, off, 32);
    if (lane == 0) xsum[g * Mdim + m] = s;
}

// Main: 256 blocks = 64 n-tiles (BN=128) x KSPLIT=4, 1 block/CU (148 KB LDS).
// 512 threads = 8 waves = 2 m-tiles(32) x 4 n-strips(32).
// Counted-vmcnt pipeline with RAW barriers (no vmcnt drain at barriers):
// per iter: compute(g) -> WRITEX(b^1)[waits x(g+1), q outstanding] ->
// LOADX(g+2) -> WRITEQ(b^1)[waits q(g+1); x(g+2) keeps HBM busy] ->
// LOADQ(g+2)[queue refilled] -> lgkmcnt(0)+s_barrier. The HBM queue is
// never empty except ~100cy per 6400cy group slot.
__launch_bounds__(512, 2)
__global__ void qlin_kernel(const unsigned short* __restrict__ xh,
                            const unsigned short* __restrict__ xl,
                            const int* __restrict__ qw,
                            const float* __restrict__ scales,
                            const float* __restrict__ zeros,
                            const float* __restrict__ xsum,
                            float* __restrict__ pout) {
    __shared__ unsigned short lq[2][128 * 128];   // 2x32 KB [SWZ(n,k)]
    __shared__ unsigned short lxh[2][64 * 128];   // 2x16 KB
    __shared__ unsigned short lxl[2][64 * 128];   // 2x16 KB
    __shared__ float ls[NG2][128];                // 8 KB scales slice
    __shared__ float lz[NG2][128];                // 8 KB zeros slice
    __shared__ float lxs[NG2][64];                // 4 KB xsum slice

    const int tid = threadIdx.x;
    const int kh = blockIdx.x & (KSPLIT - 1);
    const int n0 = (blockIdx.x >> 2) * BN;
    const int g0 = kh * NG2;

    const int w = tid >> 6;
    const int l = tid & 63;
    const int lcol = l & 15;
    const int lhi = l >> 4;
    const int mt = (w >> 2) * 32;     // m-tile base: 0 or 32
    const int ns = (w & 3) * 32;      // n-strip base: 0,32,64,96

    const int qc = tid & 31;          // q staging: 16B col-chunk
    const int qr = tid >> 5;          // q staging: row octet
    const int xc = tid & 15;          // x staging: 8-elem chunk
    const int xm = tid >> 4;          // x staging: row

    const int c0 = n0 + ns + lcol;
    const int c1 = c0 + 16;

    int4v qv[8];
    ushort8 xga, xgb, xgc, xgd;

    auto LOADX = [&](int g) {
        const size_t kb = (size_t)g * GRP + xc * 8;
        xga = *(const ushort8*)(xh + (size_t)xm * Kdim + kb);
        xgb = *(const ushort8*)(xh + (size_t)(xm + 32) * Kdim + kb);
        xgc = *(const ushort8*)(xl + (size_t)xm * Kdim + kb);
        xgd = *(const ushort8*)(xl + (size_t)(xm + 32) * Kdim + kb);
    };
    auto LOADQ = [&](int g) {
        const size_t kb = (size_t)g * GRP + qr * 8;
        const int nc = n0 + qc * 4;
#pragma unroll
        for (int j = 0; j < 8; ++j)
            qv[j] = *(const int4v*)(qw + (kb + j) * Ndim + nc);
    };
    auto WRITEX = [&](int b) {
        *(ushort8*)&lxh[b][SWZ(xm, xc * 8)] = xga;
        *(ushort8*)&lxh[b][SWZ(xm + 32, xc * 8)] = xgb;
        *(ushort8*)&lxl[b][SWZ(xm, xc * 8)] = xgc;
        *(ushort8*)&lxl[b][SWZ(xm + 32, xc * 8)] = xgd;
    };
    auto WRITEQ = [&](int b) {        // exact int->bf16 (|q|<=128 => truncation exact)
#pragma unroll
        for (int i = 0; i < 4; ++i) {
            int4v pk;
#pragma unroll
            for (int t = 0; t < 4; ++t) {
                unsigned lo = __builtin_bit_cast(unsigned, (float)qv[2 * t][i]) >> 16;
                unsigned hi = __builtin_bit_cast(unsigned, (float)qv[2 * t + 1][i]) & 0xFFFF0000u;
                pk[t] = (int)(lo | hi);
            }
            *(int4v*)&lq[b][SWZ(qc * 4 + i, qr * 8)] = pk;
        }
    };

    f32x4 acc00 = {0,0,0,0}, acc01 = {0,0,0,0}, acc10 = {0,0,0,0}, acc11 = {0,0,0,0};

    // ---- prologue: tables + group g0 staged; q/x(g0+1) left IN FLIGHT ----
    {   // tables first (oldest in queue)
        const int tg = tid >> 5, tc = tid & 31;
        f32x4 sv = *(const f32x4*)(scales + (size_t)(g0 + tg) * Ndim + n0 + tc * 4);
        f32x4 zv = *(const f32x4*)(zeros + (size_t)(g0 + tg) * Ndim + n0 + tc * 4);
        float x0 = xsum[(g0 + (tid >> 6)) * Mdim + (tid & 63)];
        float x1 = xsum[(g0 + ((tid + 512) >> 6)) * Mdim + (tid & 63)];
        LOADX(g0);
        LOADQ(g0);
        *(f32x4*)&ls[tg][tc * 4] = sv;
        *(f32x4*)&lz[tg][tc * 4] = zv;
        (&lxs[0][0])[tid] = x0;
        (&lxs[0][0])[tid + 512] = x1;
        WRITEX(0);
        WRITEQ(0);                    // drains q(g0)
        if (1 < NG2) { LOADX(g0 + 1); LOADQ(g0 + 1); }
        asm volatile("s_waitcnt lgkmcnt(0)" ::: "memory");
        __builtin_amdgcn_s_barrier();
    }

    for (int g = 0; g < NG2; ++g) {
        const int b = g & 1;

        // compute phase: lgkm-only; x/q(g+1) arriving underneath
        f32x4 p00 = {0,0,0,0}, p01 = {0,0,0,0}, p10 = {0,0,0,0}, p11 = {0,0,0,0};
#pragma unroll
        for (int ks = 0; ks < 4; ++ks) {
            const int kk = ks * 32 + lhi * 8;
            short8 bq0 = *(const short8*)&lq[b][SWZ(ns + lcol, kk)];
            short8 bq1 = *(const short8*)&lq[b][SWZ(ns + 16 + lcol, kk)];
            short8 ah0 = *(const short8*)&lxh[b][SWZ(mt + lcol, kk)];
            short8 al0 = *(const short8*)&lxl[b][SWZ(mt + lcol, kk)];
            short8 ah1 = *(const short8*)&lxh[b][SWZ(mt + 16 + lcol, kk)];
            short8 al1 = *(const short8*)&lxl[b][SWZ(mt + 16 + lcol, kk)];
            p00 = __builtin_amdgcn_mfma_f32_16x16x32_bf16(ah0, bq0, p00, 0, 0, 0);
            p00 = __builtin_amdgcn_mfma_f32_16x16x32_bf16(al0, bq0, p00, 0, 0, 0);
            p01 = __builtin_amdgcn_mfma_f32_16x16x32_bf16(ah0, bq1, p01, 0, 0, 0);
            p01 = __builtin_amdgcn_mfma_f32_16x16x32_bf16(al0, bq1, p01, 0, 0, 0);
            p10 = __builtin_amdgcn_mfma_f32_16x16x32_bf16(ah1, bq0, p10, 0, 0, 0);
            p10 = __builtin_amdgcn_mfma_f32_16x16x32_bf16(al1, bq0, p10, 0, 0, 0);
            p11 = __builtin_amdgcn_mfma_f32_16x16x32_bf16(ah1, bq1, p11, 0, 0, 0);
            p11 = __builtin_amdgcn_mfma_f32_16x16x32_bf16(al1, bq1, p11, 0, 0, 0);
        }
        {   // group fold (LDS tables only)
            const float s0 = ls[g][ns + lcol],      z0 = lz[g][ns + lcol];
            const float s1 = ls[g][ns + 16 + lcol], z1 = lz[g][ns + 16 + lcol];
            f32x4 xs0 = *(const f32x4*)&lxs[g][mt + lhi * 4];
            f32x4 xs1 = *(const f32x4*)&lxs[g][mt + 16 + lhi * 4];
#pragma unroll
            for (int r = 0; r < 4; ++r) {
                acc00[r] += s0 * (p00[r] - z0 * xs0[r]);
                acc01[r] += s1 * (p01[r] - z1 * xs0[r]);
                acc10[r] += s0 * (p10[r] - z0 * xs1[r]);
                acc11[r] += s1 * (p11[r] - z1 * xs1[r]);
            }
        }

        if (g + 1 < NG2) {
            WRITEX(b ^ 1);                        // waits x(g+1); q(g+1) stays
            if (g + 2 < NG2) {
                LOADX(g0 + g + 2);                // outstanding during q drain
                __builtin_amdgcn_sched_barrier(0);
            }
            WRITEQ(b ^ 1);                        // waits q(g+1); x(g+2) in flight
            if (g + 2 < NG2) {
                LOADQ(g0 + g + 2);                // refill queue immediately
                __builtin_amdgcn_sched_barrier(0);
            }
            asm volatile("s_waitcnt lgkmcnt(0)" ::: "memory");
            __builtin_amdgcn_s_barrier();         // RAW: vmcnt survives
        }
    }

    const size_t ob = (size_t)kh * Mdim * Ndim;
#pragma unroll
    for (int r = 0; r < 4; ++r) {
        pout[ob + (size_t)(mt + lhi * 4 + r) * Ndim + c0] = acc00[r];
        pout[ob + (size_t)(mt + lhi * 4 + r) * Ndim + c1] = acc01[r];
        pout[ob + (size_t)(mt + 16 + lhi * 4 + r) * Ndim + c0] = acc10[r];
        pout[ob + (size_t)(mt + 16 + lhi * 4 + r) * Ndim + c1] = acc11[r];
    }
}

// out = sum of KSPLIT partials + bias
__global__ void reduce_kernel(const float* __restrict__ pout,
                              const float* __restrict__ bias,
                              float* __restrict__ out) {
    const size_t e = ((size_t)blockIdx.x * 256 + threadIdx.x) * 4;
    const int n = (int)(e & (Ndim - 1));
    f32x4 a = *(const f32x4*)(bias + n);
#pragma unroll
    for (int s = 0; s < KSPLIT; ++s) {
        f32x4 ppart = *(const f32x4*)(pout + (size_t)s * Mdim * Ndim + e);
#pragma unroll
        for (int r = 0; r < 4; ++r) a[r] += ppart[r];
    }
    *(f32x4*)(out + e) = a;
}

extern "C" void kernel_launch(void* const* d_in, const int* in_sizes, int n_in,
                              void* d_out, int out_size, void* d_ws, size_t ws_size,
                              hipStream_t stream) {
    const float* x = (const float*)d_in[0];
    const int* qw = (const int*)d_in[1];
    const float* scales = (const float*)d_in[2];
    const float* zeros = (const float*)d_in[3];
    const float* bias = (const float*)d_in[4];

    unsigned short* xh = (unsigned short*)d_ws;
    unsigned short* xl = xh + (size_t)Mdim * Kdim;
    float* xsum = (float*)(xl + (size_t)Mdim * Kdim);
    float* pout = xsum + NGRP * Mdim;
    float* out = (float*)d_out;

    prep_kernel<<<512, 256, 0, stream>>>(x, xh, xl, xsum);
    qlin_kernel<<<(Ndim / BN) * KSPLIT, 512, 0, stream>>>(xh, xl, qw, scales, zeros, xsum, pout);
    reduce_kernel<<<(Mdim * Ndim / 4) / 256, 256, 0, stream>>>(pout, bias, out);
}